// Round 13
// baseline (355.109 us; speedup 1.0000x reference)
//
#include <hip/hip_runtime.h>
#include <hip/hip_bf16.h>
#include <math.h>

#define NHEADS 16
#define DHEAD  64
#define CHDIM  80
#define RQn    6
#define RKn    2
#define RVn    2
#define TT     2048
#define DDim   1024
#define NQK    800

using frag16 = __attribute__((ext_vector_type(8))) short;
using f32x4  = __attribute__((ext_vector_type(4))) float;
using f32x16 = __attribute__((ext_vector_type(16))) float;

#define AS1(p) ((const __attribute__((address_space(1))) unsigned int*)(p))
#define AS3(p) ((__attribute__((address_space(3))) unsigned int*)(p))

static __device__ __forceinline__ unsigned short bf16_bits(float f) {
    __hip_bfloat16 h = __float2bfloat16(f);
    return *(unsigned short*)&h;
}
static __device__ __forceinline__ unsigned int pk2(float a, float b) {
    return ((unsigned int)bf16_bits(b) << 16) | (unsigned int)bf16_bits(a);
}

// ---------------- fused fp32 -> bf16 convert (r9-verbatim) ----------
__global__ __launch_bounds__(256) void cvt_all(
    const float* __restrict__ x, const float* __restrict__ wq,
    const float* __restrict__ wk, const float* __restrict__ wo,
    __hip_bfloat16* __restrict__ xb, __hip_bfloat16* __restrict__ wqk,
    __hip_bfloat16* __restrict__ wob)
{
    int bid = blockIdx.x;
    const float* src; __hip_bfloat16* dst; int n4;
    if (bid < 4096)      { src = x;  dst = xb;            n4 = 1048576; }
    else if (bid < 4576) { bid -= 4096; src = wq; dst = wqk;           n4 = 122880; }
    else if (bid < 4896) { bid -= 4576; src = wk; dst = wqk + 491520;  n4 = 81920; }
    else                 { bid -= 4896; src = wo; dst = wob;           n4 = 262144; }
    int i = bid * 256 + threadIdx.x;
    if (i < n4) {
        float4 v = *(const float4*)&src[i * 4];
        ushort4 o;
        o.x = bf16_bits(v.x); o.y = bf16_bits(v.y);
        o.z = bf16_bits(v.z); o.w = bf16_bits(v.w);
        *(ushort4*)&dst[i * 4] = o;
    }
}

// ---------- GEMM 64x128 tile, dbuf global_load_lds (r9-verbatim) ---------
__global__ __launch_bounds__(256) void gemm_bf16(
    const __hip_bfloat16* __restrict__ A, const __hip_bfloat16* __restrict__ W,
    float* __restrict__ C, int M, int N, int K)
{
    __shared__ __hip_bfloat16 Asl[2][64 * 64];
    __shared__ __hip_bfloat16 Bsl[2][128 * 64];
    const int tid = threadIdx.x;
    const int w = tid >> 6, lane = tid & 63;
    const int l16 = lane & 15, quad = lane >> 4;
    const int bm = blockIdx.y * 64, bn = blockIdx.x * 128;

    int rSA[2], cSA[2];
    #pragma unroll
    for (int j = 0; j < 2; j++) {
        int L = (w * 2 + j) * 64 + lane;
        rSA[j] = L >> 3;
        cSA[j] = (L & 7) ^ (rSA[j] & 7);
    }
    int rSB[4], cSB[4];
    #pragma unroll
    for (int j = 0; j < 4; j++) {
        int L = (w * 4 + j) * 64 + lane;
        int r = L >> 3;
        cSB[j] = (L & 7) ^ (r & 7);
        int rb = bn + r;
        rSB[j] = (rb < N) ? rb : (N - 1);
    }

    f32x4 acc[4][2];
    #pragma unroll
    for (int mt = 0; mt < 4; mt++)
        #pragma unroll
        for (int nt = 0; nt < 2; nt++)
            acc[mt][nt] = (f32x4){0.f, 0.f, 0.f, 0.f};

    const int nK = K >> 6;
    #pragma unroll
    for (int j = 0; j < 2; j++)
        __builtin_amdgcn_global_load_lds(AS1(A + (size_t)(bm + rSA[j]) * K + cSA[j] * 8),
                                         AS3(&Asl[0][(w * 2 + j) * 512]), 16, 0, 0);
    #pragma unroll
    for (int j = 0; j < 4; j++)
        __builtin_amdgcn_global_load_lds(AS1(W + (size_t)rSB[j] * K + cSB[j] * 8),
                                         AS3(&Bsl[0][(w * 4 + j) * 512]), 16, 0, 0);

    for (int kk = 0; kk < nK; kk++) {
        const int cur = kk & 1;
        __syncthreads();
        if (kk + 1 < nK) {
            const int k1 = (kk + 1) * 64;
            #pragma unroll
            for (int j = 0; j < 2; j++)
                __builtin_amdgcn_global_load_lds(AS1(A + (size_t)(bm + rSA[j]) * K + k1 + cSA[j] * 8),
                                                 AS3(&Asl[cur ^ 1][(w * 2 + j) * 512]), 16, 0, 0);
            #pragma unroll
            for (int j = 0; j < 4; j++)
                __builtin_amdgcn_global_load_lds(AS1(W + (size_t)rSB[j] * K + k1 + cSB[j] * 8),
                                                 AS3(&Bsl[cur ^ 1][(w * 4 + j) * 512]), 16, 0, 0);
        }
        #pragma unroll
        for (int ks = 0; ks < 2; ks++) {
            frag16 af[4], bf[2];
            #pragma unroll
            for (int mt = 0; mt < 4; mt++) {
                int r = mt * 16 + l16;
                af[mt] = *(const frag16*)&Asl[cur][r * 64 + (((ks * 4 + quad) ^ (r & 7)) * 8)];
            }
            #pragma unroll
            for (int nt = 0; nt < 2; nt++) {
                int r = w * 32 + nt * 16 + l16;
                bf[nt] = *(const frag16*)&Bsl[cur][r * 64 + (((ks * 4 + quad) ^ (r & 7)) * 8)];
            }
            #pragma unroll
            for (int mt = 0; mt < 4; mt++)
                #pragma unroll
                for (int nt = 0; nt < 2; nt++)
                    acc[mt][nt] = __builtin_amdgcn_mfma_f32_16x16x32_bf16(af[mt], bf[nt], acc[mt][nt], 0, 0, 0);
        }
    }
    #pragma unroll
    for (int mt = 0; mt < 4; mt++) {
        #pragma unroll
        for (int reg = 0; reg < 4; reg++) {
            int row = bm + mt * 16 + quad * 4 + reg;
            #pragma unroll
            for (int nt = 0; nt < 2; nt++) {
                int col = bn + w * 32 + nt * 16 + l16;
                if (col < N) C[(size_t)row * N + col] = acc[mt][nt][reg];
            }
        }
    }
}

// ---------------- RoPE + rank contraction (r9-verbatim) ----------
__global__ __launch_bounds__(256) void qkv_kernel(
    const float* __restrict__ ab,
    __hip_bfloat16* __restrict__ q, __hip_bfloat16* __restrict__ k,
    __hip_bfloat16* __restrict__ vT)
{
    const int tok0 = blockIdx.x * 4;
    const int w = threadIdx.x >> 6;
    const int d = threadIdx.x & 63;
    const int token = tok0 + w;
    const int b = token / TT;
    const int t = token % TT;
    __shared__ float sq[4][RQn * CHDIM];
    __shared__ float skv[4][(RKn + RVn) * CHDIM];
    __shared__ __align__(8) __hip_bfloat16 vbuf[NHEADS][DHEAD][4];
    const float* aq  = ab + (size_t)token * NQK;
    const float* akv = aq + 480;
    for (int i = d; i < RQn * CHDIM; i += 64) sq[w][i] = aq[i];
    for (int i = d; i < (RKn + RVn) * CHDIM; i += 64) skv[w][i] = akv[i];
    const int i32 = d & 31;
    float inv_freq = powf(10000.0f, -(float)i32 / 32.0f);
    float fr = (float)t * inv_freq;
    float c = cosf(fr), s = sinf(fr);
    float rot[4];
    #pragma unroll
    for (int r = 0; r < 4; r++) {
        float x1 = skv[w][r * CHDIM + NHEADS + i32];
        float x2 = skv[w][r * CHDIM + NHEADS + 32 + i32];
        rot[r] = (d < 32) ? (x1 * c + x2 * s) : (-x1 * s + x2 * c);
    }
    float bqv[RQn];
    #pragma unroll
    for (int r = 0; r < RQn; r++) bqv[r] = sq[w][r * CHDIM + NHEADS + d];
    #pragma unroll
    for (int h = 0; h < NHEADS; h++) {
        float accq = 0.0f;
        #pragma unroll
        for (int r = 0; r < RQn; r++)
            accq += sq[w][r * CHDIM + h] * bqv[r];
        q[((size_t)(b * NHEADS + h) * TT + t) * DHEAD + d] = __float2bfloat16(accq * (0.125f / 6.0f));
        float acck = 0.0f, accv = 0.0f;
        #pragma unroll
        for (int r = 0; r < RKn; r++)
            acck += skv[w][r * CHDIM + h] * rot[r];
        #pragma unroll
        for (int r = 0; r < RVn; r++)
            accv += skv[w][(RKn + r) * CHDIM + h] * rot[RKn + r];
        k[((size_t)(b * NHEADS + h) * TT + t) * DHEAD + d] = __float2bfloat16(acck * 0.5f);
        vbuf[h][d][w] = __float2bfloat16(accv * 0.5f);
    }
    __syncthreads();
    const int t0 = tok0 % TT;
    const int b0 = tok0 / TT;
    for (int row = threadIdx.x; row < NHEADS * DHEAD; row += 256) {
        int h = row >> 6, dd = row & 63;
        *(uint2*)&vT[((size_t)(b0 * NHEADS + h) * DHEAD + dd) * TT + t0] =
            *(const uint2*)&vbuf[h][dd][0];
    }
}

// ---------------- flash helpers (r9-verbatim) ----------------
static __device__ __forceinline__ void build_pfrag(
    const float* s0, const float* s1, frag16 Pf[4], const int hi, const int paddr)
{
    #pragma unroll
    for (int k2 = 0; k2 < 4; k2++) {
        const float* sF = (k2 >= 2) ? s1 : s0;
        const int bs = 8 * (k2 & 1);
        unsigned int u0a = pk2(sF[bs + 0], sF[bs + 1]);
        unsigned int u0b = pk2(sF[bs + 2], sF[bs + 3]);
        unsigned int u1a = pk2(sF[bs + 4], sF[bs + 5]);
        unsigned int u1b = pk2(sF[bs + 6], sF[bs + 7]);
        unsigned int r0a = (unsigned int)__builtin_amdgcn_ds_bpermute(paddr, (int)u0a);
        unsigned int r0b = (unsigned int)__builtin_amdgcn_ds_bpermute(paddr, (int)u0b);
        unsigned int r1a = (unsigned int)__builtin_amdgcn_ds_bpermute(paddr, (int)u1a);
        unsigned int r1b = (unsigned int)__builtin_amdgcn_ds_bpermute(paddr, (int)u1b);
        union { frag16 f; unsigned int u[4]; } pf;
        pf.u[0] = hi ? r1a : u0a;
        pf.u[1] = hi ? r1b : u0b;
        pf.u[2] = hi ? u1a : r0a;
        pf.u[3] = hi ? u1b : r0b;
        Pf[k2] = pf.f;
    }
}

static __device__ __forceinline__ void attn_tile(
    const __hip_bfloat16* __restrict__ Kc, const __hip_bfloat16* __restrict__ Vc,
    const frag16 qB[4], f32x16& O0, f32x16& O1, float& lpart,
    const int l31, const int hi, const int xi, const int paddr,
    const bool domask, const int kb0, const int qlane)
{
    f32x16 ST0 = {}, ST1 = {};
    #pragma unroll
    for (int kt4 = 0; kt4 < 4; kt4++) {
        int c8 = kt4 * 2 + hi;
        frag16 kf0 = *(const frag16*)&Kc[l31 * 64 + ((c8 ^ xi) * 8)];
        frag16 kf1 = *(const frag16*)&Kc[(32 + l31) * 64 + ((c8 ^ xi) * 8)];
        ST0 = __builtin_amdgcn_mfma_f32_32x32x16_bf16(kf0, qB[kt4], ST0, 0, 0, 0);
        ST1 = __builtin_amdgcn_mfma_f32_32x32x16_bf16(kf1, qB[kt4], ST1, 0, 0, 0);
    }
    float* s0 = (float*)&ST0;
    float* s1 = (float*)&ST1;
    if (domask) {
        int kbq = kb0 + 4 * hi;
        #pragma unroll
        for (int reg = 0; reg < 16; reg++) {
            int rowc = (reg & 3) + 8 * (reg >> 2);
            if (kbq + rowc > qlane)      s0[reg] = -1e30f;
            if (kbq + 32 + rowc > qlane) s1[reg] = -1e30f;
        }
    }
    #pragma unroll
    for (int reg = 0; reg < 16; reg++) {
        float p0 = __expf(s0[reg]);
        float p1 = __expf(s1[reg]);
        s0[reg] = p0; s1[reg] = p1;
        lpart += p0 + p1;
    }
    frag16 Pf[4];
    build_pfrag(s0, s1, Pf, hi, paddr);
    #pragma unroll
    for (int k2 = 0; k2 < 4; k2++) {
        int c8 = k2 * 2 + hi;
        frag16 vf0 = *(const frag16*)&Vc[l31 * 64 + ((c8 ^ xi) * 8)];
        frag16 vf1 = *(const frag16*)&Vc[(32 + l31) * 64 + ((c8 ^ xi) * 8)];
        O0 = __builtin_amdgcn_mfma_f32_32x32x16_bf16(vf0, Pf[k2], O0, 0, 0, 0);
        O1 = __builtin_amdgcn_mfma_f32_32x32x16_bf16(vf1, Pf[k2], O1, 0, 0, 0);
    }
}

// ------------- quarter-split uniform flash: 1024 blocks, 4/CU -------------
// Pair (qt_lo=qthalf, qt_hi=15-qthalf) = 34 tiles in order [lo 0..nlo) ++
// [hi 0..nhi). Part p covers global tiles [SB[p], SB[p+1]). All partials go
// through Op/Lp; combine sums the statically-known contributor parts.
__global__ __launch_bounds__(256, 4) void flash_mfma(
    const __hip_bfloat16* __restrict__ q, const __hip_bfloat16* __restrict__ k,
    const __hip_bfloat16* __restrict__ vT,
    float* __restrict__ Op, float* __restrict__ Lp)
{
    const int g = blockIdx.x;            // 1024
    const int part = g >> 8;
    const int pairslot = g & 255;
    const int bh = pairslot >> 3;
    const int qthalf = pairslot & 7;
    const int qt_lo = qthalf, qt_hi = 15 - qthalf;
    const int nlo = 2 * qt_lo + 2;
    const int SB[5] = {0, 8, 17, 25, 34};
    const int start = SB[part], end = SB[part + 1];
    const bool hasLo = (start < nlo);
    const bool hasHi = (end > nlo);
    const int tid = threadIdx.x;
    const int w = tid >> 6;
    const int lane = tid & 63;
    const int l31 = lane & 31;
    const int hi = lane >> 5;
    const int xi = l31 & 7;
    const int paddr = (lane ^ 32) << 2;

    __shared__ __align__(16) __hip_bfloat16 KsF[2][4096];
    __shared__ __align__(16) __hip_bfloat16 VsF[2][4096];

    const size_t base = (size_t)bh * TT * DHEAD;
    const __hip_bfloat16* qb = q + base;
    const __hip_bfloat16* kb = k + base;
    const __hip_bfloat16* vb = vT + base;

    const int ktd_lo = 2 * qt_lo + (w >> 1);
    const int ktd_hi = 2 * qt_hi + (w >> 1);
    const int qlane_lo = qt_lo * 128 + w * 32 + l31;
    const int qlane_hi = qt_hi * 128 + w * 32 + l31;

    int offK[2], offV[2];
    #pragma unroll
    for (int j = 0; j < 2; j++) {
        int Lc = w * 128 + j * 64 + lane;
        int r = Lc >> 3, c8 = Lc & 7, g8 = c8 ^ (r & 7);
        offK[j] = r * 64 + g8 * 8;
        offV[j] = r * TT + g8 * 8;
    }

    frag16 qB_lo[4], qB_hi[4];
    if (hasLo) {
        #pragma unroll
        for (int kt4 = 0; kt4 < 4; kt4++)
            qB_lo[kt4] = *(const frag16*)&qb[(size_t)qlane_lo * DHEAD + kt4 * 16 + hi * 8];
    }
    if (hasHi) {
        #pragma unroll
        for (int kt4 = 0; kt4 < 4; kt4++)
            qB_hi[kt4] = *(const frag16*)&qb[(size_t)qlane_hi * DHEAD + kt4 * 16 + hi * 8];
    }

    f32x16 Olo0 = {}, Olo1 = {}, Ohi0 = {}, Ohi1 = {};
    float l_lo = 0.0f, l_hi = 0.0f;

    // prologue: stage first physical tile
    {
        int phys0 = (start < nlo) ? start : (start - nlo);
        #pragma unroll
        for (int j = 0; j < 2; j++) {
            __builtin_amdgcn_global_load_lds(AS1(kb + (size_t)phys0 * 4096 + offK[j]),
                                             AS3(&KsF[0][w * 1024 + j * 512]), 16, 0, 0);
            __builtin_amdgcn_global_load_lds(AS1(vb + (size_t)phys0 * 64 + offV[j]),
                                             AS3(&VsF[0][w * 1024 + j * 512]), 16, 0, 0);
        }
    }

    for (int ktg = start; ktg < end; ktg++) {
        const int cur = (ktg - start) & 1;
        __syncthreads();
        if (ktg + 1 < end) {
            int pn = (ktg + 1 < nlo) ? (ktg + 1) : (ktg + 1 - nlo);
            #pragma unroll
            for (int j = 0; j < 2; j++) {
                __builtin_amdgcn_global_load_lds(AS1(kb + (size_t)pn * 4096 + offK[j]),
                                                 AS3(&KsF[cur ^ 1][w * 1024 + j * 512]), 16, 0, 0);
                __builtin_amdgcn_global_load_lds(AS1(vb + (size_t)pn * 64 + offV[j]),
                                                 AS3(&VsF[cur ^ 1][w * 1024 + j * 512]), 16, 0, 0);
            }
        }
        const __hip_bfloat16* Kc = KsF[cur];
        const __hip_bfloat16* Vc = VsF[cur];
        if (ktg < nlo) {
            int phys = ktg;
            if (phys <= ktd_lo)
                attn_tile(Kc, Vc, qB_lo, Olo0, Olo1, l_lo, l31, hi, xi, paddr,
                          phys == ktd_lo, phys * 64, qlane_lo);
        } else {
            int phys = ktg - nlo;
            if (phys <= ktd_hi)
                attn_tile(Kc, Vc, qB_hi, Ohi0, Ohi1, l_hi, l31, hi, xi, paddr,
                          phys == ktd_hi, phys * 64, qlane_hi);
        }
    }

    // ---- epilogue: store touched segment partials ----
    const int rloc = w * 32 + l31;
    if (hasLo) {
        float lother = __int_as_float(__builtin_amdgcn_ds_bpermute(paddr, __float_as_int(l_lo)));
        const int slotIdx = part * 512 + pairslot * 2 + 0;
        float* Od = Op + (size_t)slotIdx * 8192 + (size_t)rloc * 64;
        float* o0 = (float*)&Olo0;
        float* o1 = (float*)&Olo1;
        #pragma unroll
        for (int gg = 0; gg < 4; gg++) {
            int d0 = 8 * gg + 4 * hi;
            *(float4*)&Od[d0]      = (float4){o0[4*gg+0], o0[4*gg+1], o0[4*gg+2], o0[4*gg+3]};
            *(float4*)&Od[32 + d0] = (float4){o1[4*gg+0], o1[4*gg+1], o1[4*gg+2], o1[4*gg+3]};
        }
        if (hi == 0) Lp[slotIdx * 128 + rloc] = l_lo + lother;
    }
    if (hasHi) {
        float lother = __int_as_float(__builtin_amdgcn_ds_bpermute(paddr, __float_as_int(l_hi)));
        const int slotIdx = part * 512 + pairslot * 2 + 1;
        float* Od = Op + (size_t)slotIdx * 8192 + (size_t)rloc * 64;
        float* o0 = (float*)&Ohi0;
        float* o1 = (float*)&Ohi1;
        #pragma unroll
        for (int gg = 0; gg < 4; gg++) {
            int d0 = 8 * gg + 4 * hi;
            *(float4*)&Od[d0]      = (float4){o0[4*gg+0], o0[4*gg+1], o0[4*gg+2], o0[4*gg+3]};
            *(float4*)&Od[32 + d0] = (float4){o1[4*gg+0], o1[4*gg+1], o1[4*gg+2], o1[4*gg+3]};
        }
        if (hi == 0) Lp[slotIdx * 128 + rloc] = l_hi + lother;
    }
}

// -------- combine: sum contributor parts per (pair, segment), write y -------
__global__ __launch_bounds__(256) void combine(
    const float* __restrict__ Op, const float* __restrict__ Lp,
    __hip_bfloat16* __restrict__ y)
{
    int idx = blockIdx.x * 256 + threadIdx.x;   // 262144 = 65536 rows x 4 quarters
    int rowid = idx >> 2, qq = idx & 3;
    int pairslot = rowid >> 8;
    int local = rowid & 255;
    int seg = local >> 7, row = local & 127;
    int bh = pairslot >> 3, qthalf = pairslot & 7;
    int nlo = 2 * qthalf + 2;
    int qt = seg ? (15 - qthalf) : qthalf;
    int b = bh >> 4, h = bh & 15;
    int qrow = qt * 128 + row;
    const int SB[5] = {0, 8, 17, 25, 34};
    float l = 0.0f;
    float o[16] = {};
    #pragma unroll
    for (int p = 0; p < 4; p++) {
        bool use = seg ? (SB[p + 1] > nlo) : (SB[p] < nlo);
        if (use) {
            int slotIdx = p * 512 + pairslot * 2 + seg;
            l += Lp[slotIdx * 128 + row];
            const float* src = Op + (size_t)slotIdx * 8192 + (size_t)row * 64 + qq * 16;
            #pragma unroll
            for (int c = 0; c < 16; c += 4) {
                float4 v = *(const float4*)&src[c];
                o[c] += v.x; o[c+1] += v.y; o[c+2] += v.z; o[c+3] += v.w;
            }
        }
    }
    float inv = 1.0f / l;
    __hip_bfloat16* yp = y + ((size_t)(b * TT + qrow)) * DDim + h * DHEAD + qq * 16;
    uint4 u0, u1;
    u0.x = pk2(o[0] * inv,  o[1] * inv);  u0.y = pk2(o[2] * inv,  o[3] * inv);
    u0.z = pk2(o[4] * inv,  o[5] * inv);  u0.w = pk2(o[6] * inv,  o[7] * inv);
    u1.x = pk2(o[8] * inv,  o[9] * inv);  u1.y = pk2(o[10] * inv, o[11] * inv);
    u1.z = pk2(o[12] * inv, o[13] * inv); u1.w = pk2(o[14] * inv, o[15] * inv);
    *(uint4*)&yp[0] = u0;
    *(uint4*)&yp[8] = u1;
}

extern "C" void kernel_launch(void* const* d_in, const int* in_sizes, int n_in,
                              void* d_out, int out_size, void* d_ws, size_t ws_size,
                              hipStream_t stream) {
    const float* x      = (const float*)d_in[0];
    const float* W_abq  = (const float*)d_in[1];
    const float* W_abkv = (const float*)d_in[2];
    const float* W_o    = (const float*)d_in[3];
    float* out = (float*)d_out;

    char* ws = (char*)d_ws;
    __hip_bfloat16* xb   = (__hip_bfloat16*)ws;  ws += (size_t)4194304 * 2;
    __hip_bfloat16* wqk  = (__hip_bfloat16*)ws;  ws += (size_t)NQK * 1024 * 2;
    __hip_bfloat16* wo_b = (__hip_bfloat16*)ws;  ws += (size_t)1048576 * 2;
    float* abqkv = (float*)ws;                   ws += (size_t)4096 * NQK * 4;
    __hip_bfloat16* qb = (__hip_bfloat16*)ws;    ws += (size_t)4194304 * 2;
    __hip_bfloat16* kb = (__hip_bfloat16*)ws;    ws += (size_t)4194304 * 2;
    __hip_bfloat16* vT = (__hip_bfloat16*)ws;    ws += (size_t)4194304 * 2;
    __hip_bfloat16* yb = (__hip_bfloat16*)ws;    ws += (size_t)4194304 * 2;
    float* Op = (float*)ws;                      ws += (size_t)4 * 512 * 8192 * 4;
    float* Lp = (float*)ws;                      ws += (size_t)4 * 512 * 128 * 4;

    cvt_all<<<dim3(5920), dim3(256), 0, stream>>>(x, W_abq, W_abkv, W_o, xb, wqk, wo_b);
    gemm_bf16<<<dim3(7, 64), dim3(256), 0, stream>>>(xb, wqk, abqkv, 4096, NQK, 1024);
    qkv_kernel<<<dim3(1024), dim3(256), 0, stream>>>(abqkv, qb, kb, vT);
    flash_mfma<<<dim3(1024), dim3(256), 0, stream>>>(qb, kb, vT, Op, Lp);
    combine<<<dim3(1024), dim3(256), 0, stream>>>(Op, Lp, yb);
    gemm_bf16<<<dim3(8, 64), dim3(256), 0, stream>>>(yb, wo_b, out, 4096, 1024, 1024);
}

// Round 14
// 236.380 us; speedup vs baseline: 1.5023x; 1.5023x over previous
//
#include <hip/hip_runtime.h>
#include <hip/hip_bf16.h>
#include <math.h>

#define NHEADS 16
#define DHEAD  64
#define CHDIM  80
#define RQn    6
#define RKn    2
#define RVn    2
#define TT     2048
#define DDim   1024
#define NQK    800

using frag16 = __attribute__((ext_vector_type(8))) short;
using f32x4  = __attribute__((ext_vector_type(4))) float;
using f32x16 = __attribute__((ext_vector_type(16))) float;

#define AS1(p) ((const __attribute__((address_space(1))) unsigned int*)(p))
#define AS3(p) ((__attribute__((address_space(3))) unsigned int*)(p))

static __device__ __forceinline__ unsigned short bf16_bits(float f) {
    __hip_bfloat16 h = __float2bfloat16(f);
    return *(unsigned short*)&h;
}
static __device__ __forceinline__ unsigned int pk2(float a, float b) {
    return ((unsigned int)bf16_bits(b) << 16) | (unsigned int)bf16_bits(a);
}

// ---------------- fused fp32 -> bf16 convert (r9-verbatim) ----------
__global__ __launch_bounds__(256) void cvt_all(
    const float* __restrict__ x, const float* __restrict__ wq,
    const float* __restrict__ wk, const float* __restrict__ wo,
    __hip_bfloat16* __restrict__ xb, __hip_bfloat16* __restrict__ wqk,
    __hip_bfloat16* __restrict__ wob)
{
    int bid = blockIdx.x;
    const float* src; __hip_bfloat16* dst; int n4;
    if (bid < 4096)      { src = x;  dst = xb;            n4 = 1048576; }
    else if (bid < 4576) { bid -= 4096; src = wq; dst = wqk;           n4 = 122880; }
    else if (bid < 4896) { bid -= 4576; src = wk; dst = wqk + 491520;  n4 = 81920; }
    else                 { bid -= 4896; src = wo; dst = wob;           n4 = 262144; }
    int i = bid * 256 + threadIdx.x;
    if (i < n4) {
        float4 v = *(const float4*)&src[i * 4];
        ushort4 o;
        o.x = bf16_bits(v.x); o.y = bf16_bits(v.y);
        o.z = bf16_bits(v.z); o.w = bf16_bits(v.w);
        *(ushort4*)&dst[i * 4] = o;
    }
}

// ---------- GEMM 64x128 tile, dbuf global_load_lds (r9-verbatim) ---------
__global__ __launch_bounds__(256) void gemm_bf16(
    const __hip_bfloat16* __restrict__ A, const __hip_bfloat16* __restrict__ W,
    float* __restrict__ C, int M, int N, int K)
{
    __shared__ __hip_bfloat16 Asl[2][64 * 64];
    __shared__ __hip_bfloat16 Bsl[2][128 * 64];
    const int tid = threadIdx.x;
    const int w = tid >> 6, lane = tid & 63;
    const int l16 = lane & 15, quad = lane >> 4;
    const int bm = blockIdx.y * 64, bn = blockIdx.x * 128;

    int rSA[2], cSA[2];
    #pragma unroll
    for (int j = 0; j < 2; j++) {
        int L = (w * 2 + j) * 64 + lane;
        rSA[j] = L >> 3;
        cSA[j] = (L & 7) ^ (rSA[j] & 7);
    }
    int rSB[4], cSB[4];
    #pragma unroll
    for (int j = 0; j < 4; j++) {
        int L = (w * 4 + j) * 64 + lane;
        int r = L >> 3;
        cSB[j] = (L & 7) ^ (r & 7);
        int rb = bn + r;
        rSB[j] = (rb < N) ? rb : (N - 1);
    }

    f32x4 acc[4][2];
    #pragma unroll
    for (int mt = 0; mt < 4; mt++)
        #pragma unroll
        for (int nt = 0; nt < 2; nt++)
            acc[mt][nt] = (f32x4){0.f, 0.f, 0.f, 0.f};

    const int nK = K >> 6;
    #pragma unroll
    for (int j = 0; j < 2; j++)
        __builtin_amdgcn_global_load_lds(AS1(A + (size_t)(bm + rSA[j]) * K + cSA[j] * 8),
                                         AS3(&Asl[0][(w * 2 + j) * 512]), 16, 0, 0);
    #pragma unroll
    for (int j = 0; j < 4; j++)
        __builtin_amdgcn_global_load_lds(AS1(W + (size_t)rSB[j] * K + cSB[j] * 8),
                                         AS3(&Bsl[0][(w * 4 + j) * 512]), 16, 0, 0);

    for (int kk = 0; kk < nK; kk++) {
        const int cur = kk & 1;
        __syncthreads();
        if (kk + 1 < nK) {
            const int k1 = (kk + 1) * 64;
            #pragma unroll
            for (int j = 0; j < 2; j++)
                __builtin_amdgcn_global_load_lds(AS1(A + (size_t)(bm + rSA[j]) * K + k1 + cSA[j] * 8),
                                                 AS3(&Asl[cur ^ 1][(w * 2 + j) * 512]), 16, 0, 0);
            #pragma unroll
            for (int j = 0; j < 4; j++)
                __builtin_amdgcn_global_load_lds(AS1(W + (size_t)rSB[j] * K + k1 + cSB[j] * 8),
                                                 AS3(&Bsl[cur ^ 1][(w * 4 + j) * 512]), 16, 0, 0);
        }
        #pragma unroll
        for (int ks = 0; ks < 2; ks++) {
            frag16 af[4], bf[2];
            #pragma unroll
            for (int mt = 0; mt < 4; mt++) {
                int r = mt * 16 + l16;
                af[mt] = *(const frag16*)&Asl[cur][r * 64 + (((ks * 4 + quad) ^ (r & 7)) * 8)];
            }
            #pragma unroll
            for (int nt = 0; nt < 2; nt++) {
                int r = w * 32 + nt * 16 + l16;
                bf[nt] = *(const frag16*)&Bsl[cur][r * 64 + (((ks * 4 + quad) ^ (r & 7)) * 8)];
            }
            #pragma unroll
            for (int mt = 0; mt < 4; mt++)
                #pragma unroll
                for (int nt = 0; nt < 2; nt++)
                    acc[mt][nt] = __builtin_amdgcn_mfma_f32_16x16x32_bf16(af[mt], bf[nt], acc[mt][nt], 0, 0, 0);
        }
    }
    #pragma unroll
    for (int mt = 0; mt < 4; mt++) {
        #pragma unroll
        for (int reg = 0; reg < 4; reg++) {
            int row = bm + mt * 16 + quad * 4 + reg;
            #pragma unroll
            for (int nt = 0; nt < 2; nt++) {
                int col = bn + w * 32 + nt * 16 + l16;
                if (col < N) C[(size_t)row * N + col] = acc[mt][nt][reg];
            }
        }
    }
}

// ---------------- RoPE + rank contraction (r9-verbatim) ----------
__global__ __launch_bounds__(256) void qkv_kernel(
    const float* __restrict__ ab,
    __hip_bfloat16* __restrict__ q, __hip_bfloat16* __restrict__ k,
    __hip_bfloat16* __restrict__ vT)
{
    const int tok0 = blockIdx.x * 4;
    const int w = threadIdx.x >> 6;
    const int d = threadIdx.x & 63;
    const int token = tok0 + w;
    const int b = token / TT;
    const int t = token % TT;
    __shared__ float sq[4][RQn * CHDIM];
    __shared__ float skv[4][(RKn + RVn) * CHDIM];
    __shared__ __align__(8) __hip_bfloat16 vbuf[NHEADS][DHEAD][4];
    const float* aq  = ab + (size_t)token * NQK;
    const float* akv = aq + 480;
    for (int i = d; i < RQn * CHDIM; i += 64) sq[w][i] = aq[i];
    for (int i = d; i < (RKn + RVn) * CHDIM; i += 64) skv[w][i] = akv[i];
    const int i32 = d & 31;
    float inv_freq = powf(10000.0f, -(float)i32 / 32.0f);
    float fr = (float)t * inv_freq;
    float c = cosf(fr), s = sinf(fr);
    float rot[4];
    #pragma unroll
    for (int r = 0; r < 4; r++) {
        float x1 = skv[w][r * CHDIM + NHEADS + i32];
        float x2 = skv[w][r * CHDIM + NHEADS + 32 + i32];
        rot[r] = (d < 32) ? (x1 * c + x2 * s) : (-x1 * s + x2 * c);
    }
    float bqv[RQn];
    #pragma unroll
    for (int r = 0; r < RQn; r++) bqv[r] = sq[w][r * CHDIM + NHEADS + d];
    #pragma unroll
    for (int h = 0; h < NHEADS; h++) {
        float accq = 0.0f;
        #pragma unroll
        for (int r = 0; r < RQn; r++)
            accq += sq[w][r * CHDIM + h] * bqv[r];
        q[((size_t)(b * NHEADS + h) * TT + t) * DHEAD + d] = __float2bfloat16(accq * (0.125f / 6.0f));
        float acck = 0.0f, accv = 0.0f;
        #pragma unroll
        for (int r = 0; r < RKn; r++)
            acck += skv[w][r * CHDIM + h] * rot[r];
        #pragma unroll
        for (int r = 0; r < RVn; r++)
            accv += skv[w][(RKn + r) * CHDIM + h] * rot[RKn + r];
        k[((size_t)(b * NHEADS + h) * TT + t) * DHEAD + d] = __float2bfloat16(acck * 0.5f);
        vbuf[h][d][w] = __float2bfloat16(accv * 0.5f);
    }
    __syncthreads();
    const int t0 = tok0 % TT;
    const int b0 = tok0 / TT;
    for (int row = threadIdx.x; row < NHEADS * DHEAD; row += 256) {
        int h = row >> 6, dd = row & 63;
        *(uint2*)&vT[((size_t)(b0 * NHEADS + h) * DHEAD + dd) * TT + t0] =
            *(const uint2*)&vbuf[h][dd][0];
    }
}

// ---------------- flash helpers (r9-verbatim) ----------------
static __device__ __forceinline__ void build_pfrag(
    const float* s0, const float* s1, frag16 Pf[4], const int hi, const int paddr)
{
    #pragma unroll
    for (int k2 = 0; k2 < 4; k2++) {
        const float* sF = (k2 >= 2) ? s1 : s0;
        const int bs = 8 * (k2 & 1);
        unsigned int u0a = pk2(sF[bs + 0], sF[bs + 1]);
        unsigned int u0b = pk2(sF[bs + 2], sF[bs + 3]);
        unsigned int u1a = pk2(sF[bs + 4], sF[bs + 5]);
        unsigned int u1b = pk2(sF[bs + 6], sF[bs + 7]);
        unsigned int r0a = (unsigned int)__builtin_amdgcn_ds_bpermute(paddr, (int)u0a);
        unsigned int r0b = (unsigned int)__builtin_amdgcn_ds_bpermute(paddr, (int)u0b);
        unsigned int r1a = (unsigned int)__builtin_amdgcn_ds_bpermute(paddr, (int)u1a);
        unsigned int r1b = (unsigned int)__builtin_amdgcn_ds_bpermute(paddr, (int)u1b);
        union { frag16 f; unsigned int u[4]; } pf;
        pf.u[0] = hi ? r1a : u0a;
        pf.u[1] = hi ? r1b : u0b;
        pf.u[2] = hi ? u1a : r0a;
        pf.u[3] = hi ? u1b : r0b;
        Pf[k2] = pf.f;
    }
}

static __device__ __forceinline__ void attn_tile(
    const __hip_bfloat16* __restrict__ Kc, const __hip_bfloat16* __restrict__ Vc,
    const frag16 qB[4], f32x16& O0, f32x16& O1, float& lpart,
    const int l31, const int hi, const int xi, const int paddr,
    const bool domask, const int kb0, const int qlane)
{
    f32x16 ST0 = {}, ST1 = {};
    #pragma unroll
    for (int kt4 = 0; kt4 < 4; kt4++) {
        int c8 = kt4 * 2 + hi;
        frag16 kf0 = *(const frag16*)&Kc[l31 * 64 + ((c8 ^ xi) * 8)];
        frag16 kf1 = *(const frag16*)&Kc[(32 + l31) * 64 + ((c8 ^ xi) * 8)];
        ST0 = __builtin_amdgcn_mfma_f32_32x32x16_bf16(kf0, qB[kt4], ST0, 0, 0, 0);
        ST1 = __builtin_amdgcn_mfma_f32_32x32x16_bf16(kf1, qB[kt4], ST1, 0, 0, 0);
    }
    float* s0 = (float*)&ST0;
    float* s1 = (float*)&ST1;
    if (domask) {
        int kbq = kb0 + 4 * hi;
        #pragma unroll
        for (int reg = 0; reg < 16; reg++) {
            int rowc = (reg & 3) + 8 * (reg >> 2);
            if (kbq + rowc > qlane)      s0[reg] = -1e30f;
            if (kbq + 32 + rowc > qlane) s1[reg] = -1e30f;
        }
    }
    #pragma unroll
    for (int reg = 0; reg < 16; reg++) {
        float p0 = __expf(s0[reg]);
        float p1 = __expf(s1[reg]);
        s0[reg] = p0; s1[reg] = p1;
        lpart += p0 + p1;
    }
    frag16 Pf[4];
    build_pfrag(s0, s1, Pf, hi, paddr);
    #pragma unroll
    for (int k2 = 0; k2 < 4; k2++) {
        int c8 = k2 * 2 + hi;
        frag16 vf0 = *(const frag16*)&Vc[l31 * 64 + ((c8 ^ xi) * 8)];
        frag16 vf1 = *(const frag16*)&Vc[(32 + l31) * 64 + ((c8 ^ xi) * 8)];
        O0 = __builtin_amdgcn_mfma_f32_32x32x16_bf16(vf0, Pf[k2], O0, 0, 0, 0);
        O1 = __builtin_amdgcn_mfma_f32_32x32x16_bf16(vf1, Pf[k2], O1, 0, 0, 0);
    }
}

// --- coalesced partial store: Op layout [slot][d:64][row:128] ---
// MFMA C-layout has qrow in the lane dim -> consecutive lanes write
// consecutive addresses (256B contiguous per store instr, no RFO churn).
static __device__ __forceinline__ void store_partial(
    float* __restrict__ Op, float* __restrict__ Lp, int slotIdx,
    const f32x16& O0, const f32x16& O1, float lsum,
    int rloc, int hi)
{
    float* base = Op + (size_t)slotIdx * 8192;
    const float* o0 = (const float*)&O0;
    const float* o1 = (const float*)&O1;
    #pragma unroll
    for (int reg = 0; reg < 16; reg++) {
        int d = (reg & 3) + 8 * (reg >> 2) + 4 * hi;
        base[d * 128 + rloc]        = o0[reg];
        base[(32 + d) * 128 + rloc] = o1[reg];
    }
    if (hi == 0) Lp[slotIdx * 128 + rloc] = lsum;
}

// ------------- quarter-split uniform flash: 1024 blocks, 4/CU -------------
__global__ __launch_bounds__(256, 4) void flash_mfma(
    const __hip_bfloat16* __restrict__ q, const __hip_bfloat16* __restrict__ k,
    const __hip_bfloat16* __restrict__ vT,
    float* __restrict__ Op, float* __restrict__ Lp)
{
    const int g = blockIdx.x;            // 1024
    const int part = g >> 8;
    const int pairslot = g & 255;
    const int bh = pairslot >> 3;
    const int qthalf = pairslot & 7;
    const int qt_lo = qthalf, qt_hi = 15 - qthalf;
    const int nlo = 2 * qt_lo + 2;
    const int SB[5] = {0, 8, 17, 25, 34};
    const int start = SB[part], end = SB[part + 1];
    const bool hasLo = (start < nlo);
    const bool hasHi = (end > nlo);
    const int tid = threadIdx.x;
    const int w = tid >> 6;
    const int lane = tid & 63;
    const int l31 = lane & 31;
    const int hi = lane >> 5;
    const int xi = l31 & 7;
    const int paddr = (lane ^ 32) << 2;

    __shared__ __align__(16) __hip_bfloat16 KsF[2][4096];
    __shared__ __align__(16) __hip_bfloat16 VsF[2][4096];

    const size_t base = (size_t)bh * TT * DHEAD;
    const __hip_bfloat16* qb = q + base;
    const __hip_bfloat16* kb = k + base;
    const __hip_bfloat16* vb = vT + base;

    const int ktd_lo = 2 * qt_lo + (w >> 1);
    const int ktd_hi = 2 * qt_hi + (w >> 1);
    const int qlane_lo = qt_lo * 128 + w * 32 + l31;
    const int qlane_hi = qt_hi * 128 + w * 32 + l31;

    int offK[2], offV[2];
    #pragma unroll
    for (int j = 0; j < 2; j++) {
        int Lc = w * 128 + j * 64 + lane;
        int r = Lc >> 3, c8 = Lc & 7, g8 = c8 ^ (r & 7);
        offK[j] = r * 64 + g8 * 8;
        offV[j] = r * TT + g8 * 8;
    }

    frag16 qB_lo[4], qB_hi[4];
    if (hasLo) {
        #pragma unroll
        for (int kt4 = 0; kt4 < 4; kt4++)
            qB_lo[kt4] = *(const frag16*)&qb[(size_t)qlane_lo * DHEAD + kt4 * 16 + hi * 8];
    }
    if (hasHi) {
        #pragma unroll
        for (int kt4 = 0; kt4 < 4; kt4++)
            qB_hi[kt4] = *(const frag16*)&qb[(size_t)qlane_hi * DHEAD + kt4 * 16 + hi * 8];
    }

    f32x16 Olo0 = {}, Olo1 = {}, Ohi0 = {}, Ohi1 = {};
    float l_lo = 0.0f, l_hi = 0.0f;

    {
        int phys0 = (start < nlo) ? start : (start - nlo);
        #pragma unroll
        for (int j = 0; j < 2; j++) {
            __builtin_amdgcn_global_load_lds(AS1(kb + (size_t)phys0 * 4096 + offK[j]),
                                             AS3(&KsF[0][w * 1024 + j * 512]), 16, 0, 0);
            __builtin_amdgcn_global_load_lds(AS1(vb + (size_t)phys0 * 64 + offV[j]),
                                             AS3(&VsF[0][w * 1024 + j * 512]), 16, 0, 0);
        }
    }

    for (int ktg = start; ktg < end; ktg++) {
        const int cur = (ktg - start) & 1;
        __syncthreads();
        if (ktg + 1 < end) {
            int pn = (ktg + 1 < nlo) ? (ktg + 1) : (ktg + 1 - nlo);
            #pragma unroll
            for (int j = 0; j < 2; j++) {
                __builtin_amdgcn_global_load_lds(AS1(kb + (size_t)pn * 4096 + offK[j]),
                                                 AS3(&KsF[cur ^ 1][w * 1024 + j * 512]), 16, 0, 0);
                __builtin_amdgcn_global_load_lds(AS1(vb + (size_t)pn * 64 + offV[j]),
                                                 AS3(&VsF[cur ^ 1][w * 1024 + j * 512]), 16, 0, 0);
            }
        }
        const __hip_bfloat16* Kc = KsF[cur];
        const __hip_bfloat16* Vc = VsF[cur];
        if (ktg < nlo) {
            int phys = ktg;
            if (phys <= ktd_lo)
                attn_tile(Kc, Vc, qB_lo, Olo0, Olo1, l_lo, l31, hi, xi, paddr,
                          phys == ktd_lo, phys * 64, qlane_lo);
        } else {
            int phys = ktg - nlo;
            if (phys <= ktd_hi)
                attn_tile(Kc, Vc, qB_hi, Ohi0, Ohi1, l_hi, l31, hi, xi, paddr,
                          phys == ktd_hi, phys * 64, qlane_hi);
        }
    }

    const int rloc = w * 32 + l31;
    if (hasLo) {
        float lother = __int_as_float(__builtin_amdgcn_ds_bpermute(paddr, __float_as_int(l_lo)));
        store_partial(Op, Lp, part * 512 + pairslot * 2 + 0, Olo0, Olo1,
                      l_lo + lother, rloc, hi);
    }
    if (hasHi) {
        float lother = __int_as_float(__builtin_amdgcn_ds_bpermute(paddr, __float_as_int(l_hi)));
        store_partial(Op, Lp, part * 512 + pairslot * 2 + 1, Ohi0, Ohi1,
                      l_hi + lother, rloc, hi);
    }
}

// -------- combine: sum contributor parts per (pair, segment), write y -------
// Thread mapping: row fastest -> Op reads coalesce (4B x 64 lanes contiguous).
__global__ __launch_bounds__(256) void combine(
    const float* __restrict__ Op, const float* __restrict__ Lp,
    __hip_bfloat16* __restrict__ y)
{
    int idx = blockIdx.x * 256 + threadIdx.x;   // 262144
    int row = idx & 127;
    int qq = (idx >> 7) & 3;
    int grp = idx >> 9;                          // 0..511 = pairslot*2+seg
    int pairslot = grp >> 1, seg = grp & 1;
    int bh = pairslot >> 3, qthalf = pairslot & 7;
    int nlo = 2 * qthalf + 2;
    int qt = seg ? (15 - qthalf) : qthalf;
    int b = bh >> 4, h = bh & 15;
    int qrow = qt * 128 + row;
    const int SB[5] = {0, 8, 17, 25, 34};
    float l = 0.0f;
    float o[16] = {};
    #pragma unroll
    for (int p = 0; p < 4; p++) {
        bool use = seg ? (SB[p + 1] > nlo) : (SB[p] < nlo);
        if (use) {
            int slotIdx = p * 512 + pairslot * 2 + seg;
            l += Lp[slotIdx * 128 + row];
            const float* src = Op + (size_t)slotIdx * 8192 + (size_t)(qq * 16) * 128 + row;
            #pragma unroll
            for (int d = 0; d < 16; d++)
                o[d] += src[d * 128];
        }
    }
    float inv = 1.0f / l;
    __hip_bfloat16* yp = y + ((size_t)(b * TT + qrow)) * DDim + h * DHEAD + qq * 16;
    uint4 u0, u1;
    u0.x = pk2(o[0] * inv,  o[1] * inv);  u0.y = pk2(o[2] * inv,  o[3] * inv);
    u0.z = pk2(o[4] * inv,  o[5] * inv);  u0.w = pk2(o[6] * inv,  o[7] * inv);
    u1.x = pk2(o[8] * inv,  o[9] * inv);  u1.y = pk2(o[10] * inv, o[11] * inv);
    u1.z = pk2(o[12] * inv, o[13] * inv); u1.w = pk2(o[14] * inv, o[15] * inv);
    *(uint4*)&yp[0] = u0;
    *(uint4*)&yp[8] = u1;
}

extern "C" void kernel_launch(void* const* d_in, const int* in_sizes, int n_in,
                              void* d_out, int out_size, void* d_ws, size_t ws_size,
                              hipStream_t stream) {
    const float* x      = (const float*)d_in[0];
    const float* W_abq  = (const float*)d_in[1];
    const float* W_abkv = (const float*)d_in[2];
    const float* W_o    = (const float*)d_in[3];
    float* out = (float*)d_out;

    char* ws = (char*)d_ws;
    __hip_bfloat16* xb   = (__hip_bfloat16*)ws;  ws += (size_t)4194304 * 2;
    __hip_bfloat16* wqk  = (__hip_bfloat16*)ws;  ws += (size_t)NQK * 1024 * 2;
    __hip_bfloat16* wo_b = (__hip_bfloat16*)ws;  ws += (size_t)1048576 * 2;
    float* abqkv = (float*)ws;                   ws += (size_t)4096 * NQK * 4;
    __hip_bfloat16* qb = (__hip_bfloat16*)ws;    ws += (size_t)4194304 * 2;
    __hip_bfloat16* kb = (__hip_bfloat16*)ws;    ws += (size_t)4194304 * 2;
    __hip_bfloat16* vT = (__hip_bfloat16*)ws;    ws += (size_t)4194304 * 2;
    __hip_bfloat16* yb = (__hip_bfloat16*)ws;    ws += (size_t)4194304 * 2;
    float* Op = (float*)ws;                      ws += (size_t)4 * 512 * 8192 * 4;
    float* Lp = (float*)ws;                      ws += (size_t)4 * 512 * 128 * 4;

    cvt_all<<<dim3(5920), dim3(256), 0, stream>>>(x, W_abq, W_abkv, W_o, xb, wqk, wo_b);
    gemm_bf16<<<dim3(7, 64), dim3(256), 0, stream>>>(xb, wqk, abqkv, 4096, NQK, 1024);
    qkv_kernel<<<dim3(1024), dim3(256), 0, stream>>>(abqkv, qb, kb, vT);
    flash_mfma<<<dim3(1024), dim3(256), 0, stream>>>(qb, kb, vT, Op, Lp);
    combine<<<dim3(1024), dim3(256), 0, stream>>>(Op, Lp, yb);
    gemm_bf16<<<dim3(8, 64), dim3(256), 0, stream>>>(yb, wo_b, out, 4096, 1024, 1024);
}